// Round 1
// baseline (2472.830 us; speedup 1.0000x reference)
//
#include <hip/hip_runtime.h>

namespace {

constexpr int Bb = 512;   // batch
constexpr int Tt = 512;   // time
constexpr int Ff = 64;    // input features
constexpr int Hh = 128;   // hidden
constexpr int Gg = 384;   // 3*H

using short8  = __attribute__((ext_vector_type(8))) short;
using short4v = __attribute__((ext_vector_type(4))) short;
using f32x4   = __attribute__((ext_vector_type(4))) float;

__device__ __forceinline__ short f2bf(float f) {
  unsigned u = __float_as_uint(f);
  u += 0x7FFFu + ((u >> 16) & 1u);   // round-to-nearest-even
  return (short)(u >> 16);
}
__device__ __forceinline__ float sigm(float x) { return 1.0f / (1.0f + __expf(-x)); }
__device__ __forceinline__ float tanh_fast(float x) { return 1.0f - 2.0f / (1.0f + __expf(2.0f * x)); }

// Persistent GRU layer scan. One WG = 16 batch rows, loops over all T steps.
// Weights held as MFMA B-fragments in VGPRs for the whole kernel.
// DIN = 64 (layer 0, reads fp32 x [B,T,F]) or 128 (layers 1/2, reads bf16 h [T,B,H]).
template <int DIN>
__global__ __launch_bounds__(256, 1) void gru_scan(const void* __restrict__ in_seq,
                                                   const float* __restrict__ Wx,
                                                   const float* __restrict__ Wh,
                                                   const float* __restrict__ bias,
                                                   short* __restrict__ hout) {
  constexpr int KSX  = DIN / 32;   // K-slices of the input projection
  constexpr int ROWB = DIN * 2;    // bytes per x_buf row

  const int tid   = threadIdx.x;
  const int w     = tid >> 6;      // wave 0..3, owns h-cols [w*32, w*32+32)
  const int lane  = tid & 63;
  const int lr    = lane & 15;     // row/col within 16x16 tile
  const int lk    = lane >> 4;     // k-group
  const int rb    = blockIdx.x;    // 16-row batch block
  const int cbase = w * 32;

  __shared__ short h_buf[2][16 * 128];   // 8KB, XOR-swizzled rows (256B)
  __shared__ short x_buf[2][16 * DIN];   // staged layer input, swizzled

  // ---- load weight B-fragments into registers (bf16), once ----
  short8 bwh[3][2][4];
  short8 bwx[3][2][KSX];
#pragma unroll
  for (int g = 0; g < 3; ++g) {
#pragma unroll
    for (int tau = 0; tau < 2; ++tau) {
      const int c = g * 128 + cbase + tau * 16 + lr;
#pragma unroll
      for (int ks = 0; ks < 4; ++ks) {
        short8 v;
#pragma unroll
        for (int j = 0; j < 8; ++j) v[j] = f2bf(Wh[(ks * 32 + lk * 8 + j) * Gg + c]);
        bwh[g][tau][ks] = v;
      }
#pragma unroll
      for (int ks = 0; ks < KSX; ++ks) {
        short8 v;
#pragma unroll
        for (int j = 0; j < 8; ++j) v[j] = f2bf(Wx[(ks * 32 + lk * 8 + j) * Gg + c]);
        bwx[g][tau][ks] = v;
      }
    }
  }
  float bz[2], br[2], bn[2];
#pragma unroll
  for (int tau = 0; tau < 2; ++tau) {
    const int c = cbase + tau * 16 + lr;
    bz[tau] = bias[c];
    br[tau] = bias[128 + c];
    bn[tau] = bias[256 + c];
  }

  // zero h(0)
  for (int i = tid; i < 16 * 128; i += 256) h_buf[0][i] = 0;

  // ---- input staging (prefetch regs -> swizzled LDS) ----
  const int srow   = tid >> 4;   // 0..15
  const int schunk = tid & 15;   // 0..15

  f32x4  xf = {0.f, 0.f, 0.f, 0.f};  // layer-0 prefetch
  short8 xs = {0, 0, 0, 0, 0, 0, 0, 0};

  auto stage_load = [&](int t) {
    if constexpr (DIN == Ff) {
      const float* xin = (const float*)in_seq;
      xf = *(const f32x4*)(xin + ((rb * 16 + srow) * Tt + t) * Ff + schunk * 4);
    } else {
      const short* xin = (const short*)in_seq;
      xs = *(const short8*)(xin + ((size_t)t * Bb + rb * 16 + srow) * Hh + schunk * 8);
    }
  };
  auto stage_write = [&](int buf) {
    char* base = (char*)x_buf[buf] + srow * ROWB;
    if constexpr (DIN == Ff) {
      short4v sv;
#pragma unroll
      for (int j = 0; j < 4; ++j) sv[j] = f2bf(xf[j]);
      *(short4v*)(base + ((schunk * 8) ^ ((srow & 7) << 4))) = sv;
    } else {
      *(short8*)(base + ((schunk * 16) ^ ((srow & 7) << 4))) = xs;
    }
  };

  stage_load(0);
  stage_write(0);

  float hreg[2][4];
#pragma unroll
  for (int tau = 0; tau < 2; ++tau)
#pragma unroll
    for (int i = 0; i < 4; ++i) hreg[tau][i] = 0.f;

  __syncthreads();

  for (int t = 0; t < Tt; ++t) {
    const int pp = t & 1;
    if (t + 1 < Tt) stage_load(t + 1);   // issue next-step global loads early

    // ---- A fragments from LDS (swizzled) ----
    short8 ah[4];
#pragma unroll
    for (int ks = 0; ks < 4; ++ks)
      ah[ks] = *(const short8*)((const char*)h_buf[pp] + lr * 256 +
                                ((ks * 64 + lk * 16) ^ ((lr & 7) << 4)));
    short8 ax[KSX];
#pragma unroll
    for (int ks = 0; ks < KSX; ++ks)
      ax[ks] = *(const short8*)((const char*)x_buf[pp] + lr * ROWB +
                                ((ks * 64 + lk * 16) ^ ((lr & 7) << 4)));

    // ---- MFMA: z/r fused (x+h), n kept split (needs xn, hn separately) ----
    f32x4 aZ[2], aR[2], aXn[2], aHn[2];
#pragma unroll
    for (int tau = 0; tau < 2; ++tau) {
      const f32x4 z4 = {0.f, 0.f, 0.f, 0.f};
      aZ[tau] = z4; aR[tau] = z4; aXn[tau] = z4; aHn[tau] = z4;
#pragma unroll
      for (int ks = 0; ks < 4; ++ks) {
        aZ[tau]  = __builtin_amdgcn_mfma_f32_16x16x32_bf16(ah[ks], bwh[0][tau][ks], aZ[tau], 0, 0, 0);
        aR[tau]  = __builtin_amdgcn_mfma_f32_16x16x32_bf16(ah[ks], bwh[1][tau][ks], aR[tau], 0, 0, 0);
        aHn[tau] = __builtin_amdgcn_mfma_f32_16x16x32_bf16(ah[ks], bwh[2][tau][ks], aHn[tau], 0, 0, 0);
      }
#pragma unroll
      for (int ks = 0; ks < KSX; ++ks) {
        aZ[tau]  = __builtin_amdgcn_mfma_f32_16x16x32_bf16(ax[ks], bwx[0][tau][ks], aZ[tau], 0, 0, 0);
        aR[tau]  = __builtin_amdgcn_mfma_f32_16x16x32_bf16(ax[ks], bwx[1][tau][ks], aR[tau], 0, 0, 0);
        aXn[tau] = __builtin_amdgcn_mfma_f32_16x16x32_bf16(ax[ks], bwx[2][tau][ks], aXn[tau], 0, 0, 0);
      }
    }

    // ---- gating (fp32 h state in regs) + h writes ----
#pragma unroll
    for (int tau = 0; tau < 2; ++tau) {
      const int col = cbase + tau * 16 + lr;
#pragma unroll
      for (int i = 0; i < 4; ++i) {
        const float z = sigm(aZ[tau][i] + bz[tau]);
        const float r = sigm(aR[tau][i] + br[tau]);
        const float n = tanh_fast(aXn[tau][i] + bn[tau] + r * aHn[tau][i]);
        const float h = z * hreg[tau][i] + (1.f - z) * n;
        hreg[tau][i]  = h;
        const short hb  = f2bf(h);
        const int  hrow = lk * 4 + i;
        hout[((size_t)t * Bb + rb * 16 + hrow) * Hh + col] = hb;
        *(short*)((char*)h_buf[1 - pp] + hrow * 256 + ((col * 2) ^ ((hrow & 7) << 4))) = hb;
      }
    }

    if (t + 1 < Tt) stage_write(1 - pp);
    __syncthreads();
  }
}

// out[b,t,k] = sigmoid(h[t,b,:] @ Wd + bd), h in bf16 [T,B,H], out fp32 [B,T,H]
__global__ __launch_bounds__(256, 2) void dense_out(const short* __restrict__ hseq,
                                                    const float* __restrict__ Wd,
                                                    const float* __restrict__ bd,
                                                    float* __restrict__ out) {
  __shared__ short hs[64 * 128];   // 16KB staged h tile, swizzled
  const int tid  = threadIdx.x;
  const int w    = tid >> 6;
  const int lane = tid & 63;
  const int lr   = lane & 15;
  const int lk   = lane >> 4;
  const int m0   = blockIdx.x * 64;   // h row = t*B + b

  // stage 64 rows of h
#pragma unroll
  for (int it = 0; it < 4; ++it) {
    const int ci  = it * 256 + tid;       // 16B-chunk id
    const int row = ci >> 4;
    const int c8  = (ci & 15) * 8;
    short8 v = *(const short8*)(hseq + (size_t)(m0 + row) * Hh + c8);
    *(short8*)((char*)hs + row * 256 + ((c8 * 2) ^ ((row & 7) << 4))) = v;
  }

  // Wd B-fragments + bias
  short8 bwd[2][4];
  float  bdv[2];
#pragma unroll
  for (int tau = 0; tau < 2; ++tau) {
    const int c = w * 32 + tau * 16 + lr;
    bdv[tau] = bd[c];
#pragma unroll
    for (int ks = 0; ks < 4; ++ks) {
      short8 v;
#pragma unroll
      for (int j = 0; j < 8; ++j) v[j] = f2bf(Wd[(ks * 32 + lk * 8 + j) * Hh + c]);
      bwd[tau][ks] = v;
    }
  }
  __syncthreads();

  f32x4 acc[4][2];
#pragma unroll
  for (int mt = 0; mt < 4; ++mt)
#pragma unroll
    for (int tau = 0; tau < 2; ++tau) {
      const f32x4 z4 = {0.f, 0.f, 0.f, 0.f};
      acc[mt][tau] = z4;
    }

#pragma unroll
  for (int mt = 0; mt < 4; ++mt) {
    short8 ah[4];
#pragma unroll
    for (int ks = 0; ks < 4; ++ks) {
      const int row = mt * 16 + lr;
      ah[ks] = *(const short8*)((const char*)hs + row * 256 +
                                ((ks * 64 + lk * 16) ^ ((row & 7) << 4)));
    }
#pragma unroll
    for (int tau = 0; tau < 2; ++tau)
#pragma unroll
      for (int ks = 0; ks < 4; ++ks)
        acc[mt][tau] = __builtin_amdgcn_mfma_f32_16x16x32_bf16(ah[ks], bwd[tau][ks], acc[mt][tau], 0, 0, 0);
  }

#pragma unroll
  for (int mt = 0; mt < 4; ++mt)
#pragma unroll
    for (int tau = 0; tau < 2; ++tau) {
      const int col = w * 32 + tau * 16 + lr;
#pragma unroll
      for (int i = 0; i < 4; ++i) {
        const int m  = m0 + mt * 16 + lk * 4 + i;
        const int t  = m >> 9;       // m = t*B + b, B = 512
        const int bb = m & 511;
        out[((size_t)bb * Tt + t) * Hh + col] = sigm(acc[mt][tau][i] + bdv[tau]);
      }
    }
}

}  // namespace

extern "C" void kernel_launch(void* const* d_in, const int* in_sizes, int n_in,
                              void* d_out, int out_size, void* d_ws, size_t ws_size,
                              hipStream_t stream) {
  const float* x   = (const float*)d_in[0];   // [B,T,F]
  const float* Wx0 = (const float*)d_in[1];   // [F,3H]
  const float* Wxr = (const float*)d_in[2];   // [L-1,H,3H]
  const float* Wh  = (const float*)d_in[3];   // [L,H,3H]
  const float* b   = (const float*)d_in[4];   // [L,3H]
  const float* Wd  = (const float*)d_in[5];   // [H,H]
  const float* bd  = (const float*)d_in[6];   // [H]
  float* out = (float*)d_out;

  short* hX = (short*)d_ws;                       // [T,B,H] bf16 (67MB)
  short* hY = hX + (size_t)Tt * Bb * Hh;          // [T,B,H] bf16 (67MB)

  gru_scan<64><<<Bb / 16, 256, 0, stream>>>(x, Wx0, Wh, b, hX);
  gru_scan<128><<<Bb / 16, 256, 0, stream>>>(hX, Wxr, Wh + (size_t)Hh * Gg, b + Gg, hY);
  gru_scan<128><<<Bb / 16, 256, 0, stream>>>(hY, Wxr + (size_t)Hh * Gg, Wh + 2 * (size_t)Hh * Gg,
                                             b + 2 * Gg, hX);
  dense_out<<<(Tt * Bb) / 64, 256, 0, stream>>>(hX, Wd, bd, out);
}

// Round 2
// 2095.367 us; speedup vs baseline: 1.1801x; 1.1801x over previous
//
#include <hip/hip_runtime.h>

namespace {

constexpr int Bb = 512;   // batch
constexpr int Tt = 512;   // time
constexpr int Ff = 64;    // input features
constexpr int Hh = 128;   // hidden
constexpr int Gg = 384;   // 3*H

using short8  = __attribute__((ext_vector_type(8))) short;
using short4v = __attribute__((ext_vector_type(4))) short;
using f32x4   = __attribute__((ext_vector_type(4))) float;

__device__ __forceinline__ short f2bf(float f) {
  unsigned u = __float_as_uint(f);
  u += 0x7FFFu + ((u >> 16) & 1u);   // round-to-nearest-even
  return (short)(u >> 16);
}
__device__ __forceinline__ float sigm(float x) { return 1.0f / (1.0f + __expf(-x)); }
__device__ __forceinline__ float tanh_fast(float x) { return 1.0f - 2.0f / (1.0f + __expf(2.0f * x)); }

// Persistent GRU layer scan. One WG = 16 batch rows, 8 waves, each wave owns 16
// hidden columns. Loops over all T steps; weights live in VGPRs as MFMA
// B-fragments. h state: fp32 in regs (for z*h) + bf16 in swizzled LDS (for
// cross-wave MFMA A-fragments). Layer input x is prefetched one step ahead
// directly into per-lane A-fragment registers (no LDS staging).
// Manual barrier (lgkmcnt-only) keeps global loads/stores out of the per-step
// critical path. DENSE=true fuses the sigmoid output head (layer 2).
template <int DIN, bool DENSE>
__global__ __launch_bounds__(512, 1) void gru_scan(const void* __restrict__ in_seq,
                                                   const float* __restrict__ Wx,
                                                   const float* __restrict__ Wh,
                                                   const float* __restrict__ bias,
                                                   short* __restrict__ hout,
                                                   const float* __restrict__ Wd,
                                                   const float* __restrict__ bd,
                                                   float* __restrict__ out) {
  constexpr int KSX = DIN / 32;    // K-slices of the input projection

  const int tid  = threadIdx.x;
  const int w    = tid >> 6;       // wave 0..7, owns h-cols [w*16, w*16+16)
  const int lane = tid & 63;
  const int lr   = lane & 15;      // row (A) / col (B,C) within 16x16 tile
  const int lk   = lane >> 4;      // k-group
  const int rb   = blockIdx.x;     // 16-row batch block
  const int col  = w * 16 + lr;    // this lane's hidden column

  __shared__ short h_buf[2][16 * 128];   // 8KB, rows 256B, XOR-swizzled

  // ---- weight B-fragments into registers (bf16), once ----
  short8 bwh[3][4];
  short8 bwx[3][KSX];
#pragma unroll
  for (int g = 0; g < 3; ++g) {
#pragma unroll
    for (int ks = 0; ks < 4; ++ks) {
      short8 v;
#pragma unroll
      for (int j = 0; j < 8; ++j) v[j] = f2bf(Wh[(ks * 32 + lk * 8 + j) * Gg + g * 128 + col]);
      bwh[g][ks] = v;
    }
#pragma unroll
    for (int ks = 0; ks < KSX; ++ks) {
      short8 v;
#pragma unroll
      for (int j = 0; j < 8; ++j) v[j] = f2bf(Wx[(ks * 32 + lk * 8 + j) * Gg + g * 128 + col]);
      bwx[g][ks] = v;
    }
  }
  const float bz = bias[col];
  const float brr = bias[128 + col];
  const float bn = bias[256 + col];

  short8 bwd[4];
  float  bdv = 0.f;
  if constexpr (DENSE) {
#pragma unroll
    for (int ks = 0; ks < 4; ++ks) {
      short8 v;
#pragma unroll
      for (int j = 0; j < 8; ++j) v[j] = f2bf(Wd[(ks * 32 + lk * 8 + j) * Hh + col]);
      bwd[ks] = v;
    }
    bdv = bd[col];
  }

  for (int i = tid; i < 16 * 128; i += 512) h_buf[0][i] = 0;

  // ---- x prefetch: per-lane A-fragments straight from global ----
  f32x4  xraw[4];   // DIN==64 path (fp32 input, convert at use)
  short8 xbf[KSX];  // DIN==128 path (bf16 input, direct)

  auto issue_x = [&](int t) {
    if constexpr (DIN == 64) {
      const float* base = (const float*)in_seq + ((size_t)(rb * 16 + lr) * Tt + t) * Ff + lk * 8;
#pragma unroll
      for (int ks = 0; ks < 2; ++ks) {
        xraw[ks * 2]     = *(const f32x4*)(base + ks * 32);
        xraw[ks * 2 + 1] = *(const f32x4*)(base + ks * 32 + 4);
      }
    } else {
      const short* base = (const short*)in_seq + ((size_t)t * Bb + rb * 16 + lr) * Hh + lk * 8;
#pragma unroll
      for (int ks = 0; ks < KSX; ++ks) xbf[ks] = *(const short8*)(base + ks * 32);
    }
  };

  issue_x(0);
  float hreg[4] = {0.f, 0.f, 0.f, 0.f};
  __syncthreads();

  for (int t = 0; t < Tt; ++t) {
    const int pp = t & 1;

    // current-step x fragments (convert fp32 path now; loads were issued last step)
    short8 ax[KSX];
    if constexpr (DIN == 64) {
#pragma unroll
      for (int ks = 0; ks < 2; ++ks) {
        short8 v;
#pragma unroll
        for (int j = 0; j < 4; ++j) {
          v[j]     = f2bf(xraw[ks * 2][j]);
          v[4 + j] = f2bf(xraw[ks * 2 + 1][j]);
        }
        ax[ks] = v;
      }
    } else {
#pragma unroll
      for (int ks = 0; ks < KSX; ++ks) ax[ks] = xbf[ks];
    }
    if (t + 1 < Tt) issue_x(t + 1);   // fire-and-forget; never drained in-loop

    // A-fragments of h(t-1) from swizzled LDS
    short8 ah[4];
#pragma unroll
    for (int ks = 0; ks < 4; ++ks)
      ah[ks] = *(const short8*)((const char*)h_buf[pp] + lr * 256 +
                                ((ks * 64 + lk * 16) ^ ((lr & 7) << 4)));

    if constexpr (DENSE) {
      // fused output head on h(t-1) — reuses ah, independent of recurrent chain
      if (t > 0) {
        f32x4 aD = {0.f, 0.f, 0.f, 0.f};
#pragma unroll
        for (int ks = 0; ks < 4; ++ks)
          aD = __builtin_amdgcn_mfma_f32_16x16x32_bf16(ah[ks], bwd[ks], aD, 0, 0, 0);
#pragma unroll
        for (int i = 0; i < 4; ++i)
          out[((size_t)(rb * 16 + lk * 4 + i) * Tt + (t - 1)) * Hh + col] = sigm(aD[i] + bdv);
      }
    } else {
      // coalesced store of h(t-1) to global (8B/lane), fire-and-forget
      if (t > 0) {
        const int r = tid >> 5, c = tid & 31;
        short4v v = *(const short4v*)((const char*)h_buf[pp] + r * 256 +
                                      ((c * 8) ^ ((r & 7) << 4)));
        *(short4v*)(hout + ((size_t)(t - 1) * Bb + rb * 16 + r) * Hh + c * 4) = v;
      }
    }

    // recurrent + input MFMAs (z/r fused x+h; n split: needs xn, hn separately)
    f32x4 aZ = {0.f, 0.f, 0.f, 0.f}, aR = aZ, aXn = aZ, aHn = aZ;
#pragma unroll
    for (int ks = 0; ks < 4; ++ks) {
      aZ  = __builtin_amdgcn_mfma_f32_16x16x32_bf16(ah[ks], bwh[0][ks], aZ, 0, 0, 0);
      aR  = __builtin_amdgcn_mfma_f32_16x16x32_bf16(ah[ks], bwh[1][ks], aR, 0, 0, 0);
      aHn = __builtin_amdgcn_mfma_f32_16x16x32_bf16(ah[ks], bwh[2][ks], aHn, 0, 0, 0);
    }
#pragma unroll
    for (int ks = 0; ks < KSX; ++ks) {
      aZ  = __builtin_amdgcn_mfma_f32_16x16x32_bf16(ax[ks], bwx[0][ks], aZ, 0, 0, 0);
      aR  = __builtin_amdgcn_mfma_f32_16x16x32_bf16(ax[ks], bwx[1][ks], aR, 0, 0, 0);
      aXn = __builtin_amdgcn_mfma_f32_16x16x32_bf16(ax[ks], bwx[2][ks], aXn, 0, 0, 0);
    }

    // gating
#pragma unroll
    for (int i = 0; i < 4; ++i) {
      const float z = sigm(aZ[i] + bz);
      const float r = sigm(aR[i] + brr);
      const float n = tanh_fast(aXn[i] + bn + r * aHn[i]);
      const float h = z * hreg[i] + (1.f - z) * n;
      hreg[i] = h;
      const int hrow = lk * 4 + i;
      *(short*)((char*)h_buf[1 - pp] + hrow * 256 + ((col * 2) ^ ((hrow & 7) << 4))) = f2bf(h);
    }

    // manual barrier: wait LDS only — global ops stay in flight
    __builtin_amdgcn_sched_barrier(0);
    asm volatile("s_waitcnt lgkmcnt(0)" ::: "memory");
    __builtin_amdgcn_s_barrier();
    __builtin_amdgcn_sched_barrier(0);
  }

  // epilogue: h(Tt-1) sits in h_buf[0] (Tt even)
  if constexpr (DENSE) {
    short8 ah[4];
#pragma unroll
    for (int ks = 0; ks < 4; ++ks)
      ah[ks] = *(const short8*)((const char*)h_buf[0] + lr * 256 +
                                ((ks * 64 + lk * 16) ^ ((lr & 7) << 4)));
    f32x4 aD = {0.f, 0.f, 0.f, 0.f};
#pragma unroll
    for (int ks = 0; ks < 4; ++ks)
      aD = __builtin_amdgcn_mfma_f32_16x16x32_bf16(ah[ks], bwd[ks], aD, 0, 0, 0);
#pragma unroll
    for (int i = 0; i < 4; ++i)
      out[((size_t)(rb * 16 + lk * 4 + i) * Tt + (Tt - 1)) * Hh + col] = sigm(aD[i] + bdv);
  } else {
    const int r = tid >> 5, c = tid & 31;
    short4v v = *(const short4v*)((const char*)h_buf[0] + r * 256 +
                                  ((c * 8) ^ ((r & 7) << 4)));
    *(short4v*)(hout + ((size_t)(Tt - 1) * Bb + rb * 16 + r) * Hh + c * 4) = v;
  }
}

}  // namespace

extern "C" void kernel_launch(void* const* d_in, const int* in_sizes, int n_in,
                              void* d_out, int out_size, void* d_ws, size_t ws_size,
                              hipStream_t stream) {
  const float* x   = (const float*)d_in[0];   // [B,T,F]
  const float* Wx0 = (const float*)d_in[1];   // [F,3H]
  const float* Wxr = (const float*)d_in[2];   // [L-1,H,3H]
  const float* Wh  = (const float*)d_in[3];   // [L,3H] per-layer [H,3H]
  const float* b   = (const float*)d_in[4];   // [L,3H]
  const float* Wd  = (const float*)d_in[5];   // [H,H]
  const float* bd  = (const float*)d_in[6];   // [H]
  float* out = (float*)d_out;

  short* hX = (short*)d_ws;                   // [T,B,H] bf16 (67MB)
  short* hY = hX + (size_t)Tt * Bb * Hh;      // [T,B,H] bf16 (67MB)

  gru_scan<64, false><<<Bb / 16, 512, 0, stream>>>(x, Wx0, Wh, b, hX,
                                                   nullptr, nullptr, nullptr);
  gru_scan<128, false><<<Bb / 16, 512, 0, stream>>>(hX, Wxr, Wh + (size_t)Hh * Gg,
                                                    b + Gg, hY, nullptr, nullptr, nullptr);
  gru_scan<128, true><<<Bb / 16, 512, 0, stream>>>(hY, Wxr + (size_t)Hh * Gg,
                                                   Wh + 2 * (size_t)Hh * Gg, b + 2 * Gg,
                                                   nullptr, Wd, bd, out);
}

// Round 5
// 2031.962 us; speedup vs baseline: 1.2170x; 1.0312x over previous
//
#include <hip/hip_runtime.h>

namespace {

constexpr int Bb = 512, Tt = 512, Ff = 64, Hh = 128, Gg = 384;

using short8  = __attribute__((ext_vector_type(8))) short;
using short4v = __attribute__((ext_vector_type(4))) short;
using f32x4   = __attribute__((ext_vector_type(4))) float;

__device__ __forceinline__ short f2bf(float f) {
  unsigned u = __float_as_uint(f);
  u += 0x7FFFu + ((u >> 16) & 1u);   // round-to-nearest-even
  return (short)(u >> 16);
}
__device__ __forceinline__ float sigm(float x) { return 1.0f / (1.0f + __expf(-x)); }
__device__ __forceinline__ float tanh_fast(float x) { return 1.0f - 2.0f / (1.0f + __expf(2.0f * x)); }

// async global->LDS, 16B per lane; dest = wave-uniform base + lane*16 (linear).
__device__ __forceinline__ void gl_lds16(const char* g, char* l) {
  __builtin_amdgcn_global_load_lds((const __attribute__((address_space(1))) void*)g,
                                   (__attribute__((address_space(3))) void*)l, 16, 0, 0);
}

// x [B,T,F] fp32 -> swizzled bf16 tile stream xT: [Tt][32][16 rows x 128B],
// element col c of row r at byte (c*2) ^ ((r&7)<<4) within the row.
__global__ __launch_bounds__(256, 4) void xpose(const float* __restrict__ x,
                                                char* __restrict__ xT) {
  const int gid = blockIdx.x * 256 + threadIdx.x;  // = b*Tt + t
  const int t = gid & (Tt - 1), b = gid >> 9;
  const int rb = b >> 4, r = b & 15;
  const f32x4* px = (const f32x4*)(x + (size_t)gid * Ff);
  char* row = xT + (((size_t)t * 32 + rb) * 2048) + r * 128;
  const int swz = (r & 7) << 4;
#pragma unroll
  for (int m = 0; m < 8; ++m) {
    f32x4 a = px[2 * m], c = px[2 * m + 1];
    short8 o;
#pragma unroll
    for (int j = 0; j < 4; ++j) { o[j] = f2bf(a[j]); o[4 + j] = f2bf(c[j]); }
    *(short8*)(row + ((m * 16) ^ swz)) = o;
  }
}

// Sequential GRU layer scan, time-blocked staging. One WG = 16 batch rows,
// 8 waves x 16 hidden cols. Input arrives as swizzled [16][DIN] tile images
// (4KB or 2KB per (t,rb)); 8-step blocks staged into LDS via global_load_lds
// (double-buffered, counted vmcnt(6) once per block — never drained to 0).
// Steady-state step: ds_read frags -> MFMA -> gating -> ds_write h ->
// lgkmcnt-only barrier -> stream h/out (fire-and-forget). No vmem waits.
template <int DIN, bool DENSE>
__global__ __launch_bounds__(512, 1) void gru_scan(
    const char* __restrict__ in_tiles,   // [Tt][32][TILE] swizzled images
    const float* __restrict__ Wx, const float* __restrict__ Wh,
    const float* __restrict__ bias,
    short* __restrict__ hout,            // [Tt][32][2048 shorts] or null
    const float* __restrict__ Wd, const float* __restrict__ bd,
    float* __restrict__ out) {
  constexpr int KSX  = DIN / 32;
  constexpr int TILE = 16 * DIN * 2;     // bytes per step tile (2048/4096)
  constexpr int XBUF = 8 * TILE;         // one 8-step block
  constexpr int LI   = TILE / 1024;      // global_load_lds instrs per tile
  constexpr int SMEM = 2 * XBUF + 2 * 4096 + (DENSE ? 2 * 8192 : 0);
  __shared__ char smem[SMEM];
  char* const xb0 = smem;
  char* const hb0 = smem + 2 * XBUF;
  char* const ob0 = smem + 2 * XBUF + 2 * 4096;

  const int tid = threadIdx.x;
  const int w = tid >> 6, lane = tid & 63;
  const int lr = lane & 15, lk = lane >> 4;
  const int rb = blockIdx.x;
  const int col = w * 16 + lr;

  // prologue: issue block-0 stage loads first (hide under weight setup)
  {
    const char* src0 = in_tiles + ((size_t)w * 32 + rb) * TILE;
#pragma unroll
    for (int i = 0; i < LI; ++i)
      gl_lds16(src0 + i * 1024 + lane * 16, xb0 + w * TILE + i * 1024);
  }

  // ---- weights -> MFMA B-fragments in VGPRs (bf16), once ----
  short8 bwh[3][4], bwx[3][KSX];
#pragma unroll
  for (int g = 0; g < 3; ++g) {
#pragma unroll
    for (int ks = 0; ks < 4; ++ks) {
      short8 v;
#pragma unroll
      for (int j = 0; j < 8; ++j) v[j] = f2bf(Wh[(ks * 32 + lk * 8 + j) * Gg + g * 128 + col]);
      bwh[g][ks] = v;
    }
#pragma unroll
    for (int ks = 0; ks < KSX; ++ks) {
      short8 v;
#pragma unroll
      for (int j = 0; j < 8; ++j) v[j] = f2bf(Wx[(ks * 32 + lk * 8 + j) * Gg + g * 128 + col]);
      bwx[g][ks] = v;
    }
  }
  const float bz = bias[col], brr = bias[Hh + col], bn = bias[2 * Hh + col];

  short8 bwd[4];
  float  bdv = 0.f;
  if constexpr (DENSE) {
#pragma unroll
    for (int ks = 0; ks < 4; ++ks) {
      short8 v;
#pragma unroll
      for (int j = 0; j < 8; ++j) v[j] = f2bf(Wd[(ks * 32 + lk * 8 + j) * Hh + col]);
      bwd[ks] = v;
    }
    bdv = bd[col];
  }

  {  // zero h(0) image
    short* hz = (short*)hb0;
    for (int i = tid; i < 2048; i += 512) hz[i] = 0;
  }

  float hreg[4] = {0.f, 0.f, 0.f, 0.f};
  asm volatile("s_waitcnt vmcnt(0)");
  __syncthreads();   // prologue only

  for (int tb = 0; tb < Tt; tb += 8) {
    char* const xcur = xb0 + ((tb >> 3) & 1) * XBUF;
    char* const xnxt = xb0 + (((tb >> 3) & 1) ^ 1) * XBUF;
    if (tb + 8 < Tt) {   // issue next block's stage loads (wave w -> tile w)
      const char* src = in_tiles + ((size_t)(tb + 8 + w) * 32 + rb) * TILE;
#pragma unroll
      for (int i = 0; i < LI; ++i)
        gl_lds16(src + i * 1024 + lane * 16, xnxt + w * TILE + i * 1024);
    }
#pragma unroll
    for (int s = 0; s < 8; ++s) {
      const int t = tb + s;
      const int pp = t & 1;
      char* const hsrc = hb0 + pp * 4096;
      char* const hdst = hb0 + (1 - pp) * 4096;

      // A-fragments from swizzled LDS
      short8 ah[4], ax[KSX];
#pragma unroll
      for (int ks = 0; ks < 4; ++ks)
        ah[ks] = *(const short8*)(hsrc + lr * 256 + ((ks * 64 + lk * 16) ^ ((lr & 7) << 4)));
      const char* xt = xcur + s * TILE + lr * (DIN * 2);
#pragma unroll
      for (int ks = 0; ks < KSX; ++ks)
        ax[ks] = *(const short8*)(xt + ((ks * 64 + lk * 16) ^ ((lr & 7) << 4)));

      f32x4 aZ = {0.f, 0.f, 0.f, 0.f}, aR = aZ, aXn = aZ, aHn = aZ;
#pragma unroll
      for (int ks = 0; ks < 4; ++ks) {
        aZ  = __builtin_amdgcn_mfma_f32_16x16x32_bf16(ah[ks], bwh[0][ks], aZ, 0, 0, 0);
        aR  = __builtin_amdgcn_mfma_f32_16x16x32_bf16(ah[ks], bwh[1][ks], aR, 0, 0, 0);
        aHn = __builtin_amdgcn_mfma_f32_16x16x32_bf16(ah[ks], bwh[2][ks], aHn, 0, 0, 0);
      }
#pragma unroll
      for (int ks = 0; ks < KSX; ++ks) {
        aZ  = __builtin_amdgcn_mfma_f32_16x16x32_bf16(ax[ks], bwx[0][ks], aZ, 0, 0, 0);
        aR  = __builtin_amdgcn_mfma_f32_16x16x32_bf16(ax[ks], bwx[1][ks], aR, 0, 0, 0);
        aXn = __builtin_amdgcn_mfma_f32_16x16x32_bf16(ax[ks], bwx[2][ks], aXn, 0, 0, 0);
      }

      if constexpr (DENSE) {   // fused head on h(t-1); independent of recurrence
        if (t > 0) {
          f32x4 aD = {0.f, 0.f, 0.f, 0.f};
#pragma unroll
          for (int ks = 0; ks < 4; ++ks)
            aD = __builtin_amdgcn_mfma_f32_16x16x32_bf16(ah[ks], bwd[ks], aD, 0, 0, 0);
#pragma unroll
          for (int i = 0; i < 4; ++i)
            *(float*)(ob0 + pp * 8192 + (lk * 4 + i) * 512 + col * 4) = sigm(aD[i] + bdv);
        }
      }

      // gating (fp32 state in regs) -> h(t) into LDS (swizzled)
#pragma unroll
      for (int i = 0; i < 4; ++i) {
        const float z = sigm(aZ[i] + bz);
        const float r = sigm(aR[i] + brr);
        const float n = tanh_fast(aXn[i] + bn + r * aHn[i]);
        const float h = z * hreg[i] + (1.f - z) * n;
        hreg[i] = h;
        const int hrow = lk * 4 + i;
        *(short*)(hdst + hrow * 256 + ((col * 2) ^ ((hrow & 7) << 4))) = f2bf(h);
      }

      // block-boundary: loads (oldest) guaranteed drained; never vmcnt(0)
      if (s == 7) asm volatile("s_waitcnt vmcnt(6)");
      __builtin_amdgcn_sched_barrier(0);
      asm volatile("s_waitcnt lgkmcnt(0)");
      __builtin_amdgcn_s_barrier();
      __builtin_amdgcn_sched_barrier(0);

      // post-barrier streaming (fire-and-forget stores)
      if constexpr (DENSE) {
        if (t > 0) {
          f32x4 v = *(const f32x4*)(ob0 + pp * 8192 + tid * 16);
          *(f32x4*)(out + ((size_t)(rb * 16 + (tid >> 5)) * Tt + (t - 1)) * Hh + (tid & 31) * 4) = v;
        }
      } else {
        short4v v = *(const short4v*)(hdst + tid * 8);
        *(short4v*)(hout + ((size_t)t * 32 + rb) * 2048 + tid * 4) = v;
      }
    }
  }

  if constexpr (DENSE) {   // final output row t = Tt-1 from h(Tt-1) in hb[0]
    short8 ah[4];
#pragma unroll
    for (int ks = 0; ks < 4; ++ks)
      ah[ks] = *(const short8*)(hb0 + lr * 256 + ((ks * 64 + lk * 16) ^ ((lr & 7) << 4)));
    f32x4 aD = {0.f, 0.f, 0.f, 0.f};
#pragma unroll
    for (int ks = 0; ks < 4; ++ks)
      aD = __builtin_amdgcn_mfma_f32_16x16x32_bf16(ah[ks], bwd[ks], aD, 0, 0, 0);
#pragma unroll
    for (int i = 0; i < 4; ++i)
      out[((size_t)(rb * 16 + lk * 4 + i) * Tt + (Tt - 1)) * Hh + col] = sigm(aD[i] + bdv);
  }
}

}  // namespace

extern "C" void kernel_launch(void* const* d_in, const int* in_sizes, int n_in,
                              void* d_out, int out_size, void* d_ws, size_t ws_size,
                              hipStream_t stream) {
  const float* x   = (const float*)d_in[0];   // [B,T,F]
  const float* Wx0 = (const float*)d_in[1];   // [F,3H]
  const float* Wxr = (const float*)d_in[2];   // [L-1,H,3H]
  const float* Wh  = (const float*)d_in[3];   // [L,H,3H]
  const float* b   = (const float*)d_in[4];   // [L,3H]
  const float* Wd  = (const float*)d_in[5];   // [H,H]
  const float* bd  = (const float*)d_in[6];   // [H]
  float* out = (float*)d_out;

  char* ws = (char*)d_ws;
  char*  xT = ws;                              // [Tt][32][2KB]  32 MiB
  short* hB = (short*)(ws + (size_t)33554432); // [Tt][32][2048] 64 MiB
  short* hA = (short*)d_out;                   // layer-0 h tiles: d_out region
                                               // (64 MiB of 134; dead before the
                                               //  final out stores overwrite it)

  xpose<<<(Bb * Tt) / 256, 256, 0, stream>>>(x, xT);
  gru_scan<64, false><<<32, 512, 0, stream>>>(xT, Wx0, Wh, b, hA,
                                              nullptr, nullptr, nullptr);
  gru_scan<128, false><<<32, 512, 0, stream>>>((const char*)hA, Wxr,
                                               Wh + (size_t)Hh * Gg, b + Gg, hB,
                                               nullptr, nullptr, nullptr);
  gru_scan<128, true><<<32, 512, 0, stream>>>((const char*)hB,
                                              Wxr + (size_t)Hh * Gg,
                                              Wh + 2 * (size_t)Hh * Gg, b + 2 * Gg,
                                              nullptr, Wd, bd, out);
}

// Round 7
// 1174.875 us; speedup vs baseline: 2.1048x; 1.7295x over previous
//
#include <hip/hip_runtime.h>

namespace {

constexpr int Bb = 512, Tt = 512, Ff = 64, Hh = 128, Gg = 384;
constexpr int CH = 64;            // time-chunk length
constexpr int NCH = Tt / CH;      // 8 chunks

using short8  = __attribute__((ext_vector_type(8))) short;
using short4v = __attribute__((ext_vector_type(4))) short;
using f32x4   = __attribute__((ext_vector_type(4))) float;

__device__ __forceinline__ short f2bf(float f) {
  unsigned u = __float_as_uint(f);
  u += 0x7FFFu + ((u >> 16) & 1u);   // round-to-nearest-even
  return (short)(u >> 16);
}
__device__ __forceinline__ float bf2f(short s) {
  return __uint_as_float(((unsigned)(unsigned short)s) << 16);
}
__device__ __forceinline__ float sigm(float x) { return 1.0f / (1.0f + __expf(-x)); }
__device__ __forceinline__ float tanh_fast(float x) { return 1.0f - 2.0f / (1.0f + __expf(2.0f * x)); }

__device__ __forceinline__ void gl_lds16(const char* g, char* l) {
  __builtin_amdgcn_global_load_lds((const __attribute__((address_space(1))) void*)g,
                                   (__attribute__((address_space(3))) void*)l, 16, 0, 0);
}

// ---------------------------------------------------------------------------
// prep: gather fp32 weights into bf16 MFMA B-fragment images (16B per lane).
// WhF[l][w][f=g*4+ks][lane]            (288 groups)
// WxF l0:[ct][ks:2] @0 ; l1 @48K ; l2 @144K (1KB groups)  (240 groups)
// WdF[ct][ks][lane]                    (32 groups)
// ---------------------------------------------------------------------------
__global__ __launch_bounds__(512, 4) void prep(const float* __restrict__ Wx0,
                                               const float* __restrict__ Wxr,
                                               const float* __restrict__ Wh,
                                               const float* __restrict__ Wd,
                                               char* __restrict__ WhF,
                                               char* __restrict__ WxF,
                                               char* __restrict__ WdF) {
  const int id = blockIdx.x * 512 + threadIdx.x;
  const int lane = id & 63, lr = lane & 15, lk = lane >> 4;
  const int q = id >> 6;
  const float* src; int col, ldn, row0; char* dst;
  if (q < 288) {         // WhF
    const int l = q / 96, rem = q % 96, w = rem / 12, f = rem % 12;
    const int g = f >> 2, ks = f & 3;
    src = Wh + (size_t)l * Hh * Gg; ldn = Gg;
    col = g * 128 + w * 16 + lr; row0 = ks * 32 + lk * 8;
    dst = WhF + (size_t)(q * 64 + lane) * 16;
  } else if (q < 528) {  // WxF
    int p = q - 288; int base;
    if (p < 48)       { src = Wx0; base = 0; }
    else if (p < 144) { src = Wxr; base = 48; p -= 48; }
    else              { src = Wxr + (size_t)Hh * Gg; base = 144; p -= 144; }
    int ct, ks;
    if (base == 0) { ct = p >> 1; ks = p & 1; } else { ct = p >> 2; ks = p & 3; }
    ldn = Gg; col = ct * 16 + lr; row0 = ks * 32 + lk * 8;
    dst = WxF + (size_t)((base + p) * 64 + lane) * 16;
  } else {               // WdF
    const int p = q - 528;
    const int ct = p >> 2, ks = p & 3;
    src = Wd; ldn = Hh; col = ct * 16 + lr; row0 = ks * 32 + lk * 8;
    dst = WdF + (size_t)(p * 64 + lane) * 16;
  }
  short8 v;
#pragma unroll
  for (int j = 0; j < 8; ++j) v[j] = f2bf(src[(size_t)(row0 + j) * ldn + col]);
  *(short8*)dst = v;
}

// ---------------------------------------------------------------------------
// gx chunk GEMM: one WG = 64 rows (one t, 64 consecutive b) x 384 cols.
// Output: C-fragment-major gx image, bias folded, bf16.
// ---------------------------------------------------------------------------
template <int KS>
__device__ void gemm_chunk(const void* __restrict__ src, int t0,
                           const char* __restrict__ wxf,
                           const float* __restrict__ bias,
                           char* __restrict__ gx, int wg, char* at) {
  constexpr int ROWB = KS * 64;   // bytes per A row
  const int tid = threadIdx.x;
  const int w = tid >> 6, lane = tid & 63, lr = lane & 15, lk = lane >> 4;
  const int trel = wg >> 3, b0 = (wg & 7) * 64;

  if constexpr (KS == 2) {
    const float* x = (const float*)src;
    const int row = tid >> 3, seg = tid & 7;
    const float* pr = x + ((size_t)(b0 + row) * Tt + t0 + trel) * Ff + seg * 8;
    f32x4 a = *(const f32x4*)pr, c = *(const f32x4*)(pr + 4);
    short8 o;
#pragma unroll
    for (int j = 0; j < 4; ++j) { o[j] = f2bf(a[j]); o[4 + j] = f2bf(c[j]); }
    *(short8*)(at + row * ROWB + ((seg * 16) ^ ((row & 7) << 4))) = o;
  } else {
    const char* h = (const char*)src + ((size_t)trel * 512 + b0) * ROWB;
    gl_lds16(h + tid * 16, at + tid * 16);
    gl_lds16(h + 8192 + tid * 16, at + 8192 + tid * 16);
    asm volatile("s_waitcnt vmcnt(0)");
  }
  __syncthreads();

  short8 bw[3][KS];
  float bs[3];
#pragma unroll
  for (int c = 0; c < 3; ++c) {
    const int ct = w * 3 + c;
    bs[c] = bias[ct * 16 + lr];
#pragma unroll
    for (int ks = 0; ks < KS; ++ks)
      bw[c][ks] = *(const short8*)(wxf + (size_t)((ct * KS + ks) * 64 + lane) * 16);
  }

#pragma unroll
  for (int rt = 0; rt < 4; ++rt) {
    const int row = rt * 16 + lr;
    short8 aa[KS];
#pragma unroll
    for (int ks = 0; ks < KS; ++ks)
      aa[ks] = *(const short8*)(at + row * ROWB + ((ks * 64 + lk * 16) ^ ((row & 7) << 4)));
#pragma unroll
    for (int c = 0; c < 3; ++c) {
      f32x4 acc = {0.f, 0.f, 0.f, 0.f};
#pragma unroll
      for (int ks = 0; ks < KS; ++ks)
        acc = __builtin_amdgcn_mfma_f32_16x16x32_bf16(aa[ks], bw[c][ks], acc, 0, 0, 0);
      const int ct = w * 3 + c, sw = ct & 7, g = ct >> 3;
      short4v o;
#pragma unroll
      for (int i = 0; i < 4; ++i) o[i] = f2bf(acc[i] + bs[c]);
      const int rb = (b0 >> 4) + rt;
      *(short4v*)(gx + (size_t)((trel * 32 + rb) * 8 + sw) * 1536 + lane * 24 + g * 8) = o;
    }
  }
}

// ---------------------------------------------------------------------------
// GRU scan over one time chunk. One WG = 16 batch rows, 8 waves x 16 cols.
// gx precomputed (3x 8B loads/lane/step, prefetched 2 ahead). 12 MFMAs/step.
// ---------------------------------------------------------------------------
template <bool DENSE>
__device__ void scan_chunk(const char* __restrict__ gx,
                           const char* __restrict__ whf,
                           short* __restrict__ hstream,
                           float* __restrict__ state, int t0,
                           const char* __restrict__ wdf,
                           const float* __restrict__ bd,
                           float* __restrict__ out, int rb,
                           char* h_buf, float* ob) {
  const int tid = threadIdx.x;
  const int w = tid >> 6, lane = tid & 63, lr = lane & 15, lk = lane >> 4;
  const int col = w * 16 + lr;

  short8 bwh[3][4];
#pragma unroll
  for (int g = 0; g < 3; ++g)
#pragma unroll
    for (int ks = 0; ks < 4; ++ks)
      bwh[g][ks] = *(const short8*)(whf + (size_t)((w * 12 + g * 4 + ks) * 64 + lane) * 16);

  short8 bwd[4]; float bdv = 0.f;
  if constexpr (DENSE) {
#pragma unroll
    for (int ks = 0; ks < 4; ++ks)
      bwd[ks] = *(const short8*)(wdf + (size_t)((w * 4 + ks) * 64 + lane) * 16);
    bdv = bd[col];
  }

  float hreg[4];
  if (t0 == 0) {
#pragma unroll
    for (int i = 0; i < 4; ++i) hreg[i] = 0.f;
    short* hz = (short*)h_buf;
    for (int i = tid; i < 2048; i += 512) hz[i] = 0;
  } else {
    f32x4 s = *(const f32x4*)(state + (size_t)(rb * 512 + tid) * 4);
#pragma unroll
    for (int i = 0; i < 4; ++i) {
      hreg[i] = s[i];
      const int hrow = lk * 4 + i;
      *(short*)(h_buf + hrow * 256 + ((col * 2) ^ ((hrow & 7) << 4))) = f2bf(s[i]);
    }
  }

  auto issue = [&](int trel, short4v* d) {
    const char* p = gx + (size_t)((trel * 32 + rb) * 8 + w) * 1536 + lane * 24;
    d[0] = *(const short4v*)p;
    d[1] = *(const short4v*)(p + 8);
    d[2] = *(const short4v*)(p + 16);
  };
  short4v pfA[3], pfB[3];
  issue(0, pfA);
  issue(1, pfB);
  __syncthreads();

  auto step = [&](int t, short4v* cur) {
    const int pp = t & 1;
    char* const hsrc = h_buf + pp * 4096;
    char* const hdst = h_buf + (1 - pp) * 4096;

    // snapshot this step's gx BEFORE the prefetch reuses the buffer
    // (round-6 bug: gating read cur[] after issue() overwrote it)
    const short4v g0 = cur[0], g1 = cur[1], g2 = cur[2];

    short8 ah[4];
#pragma unroll
    for (int ks = 0; ks < 4; ++ks)
      ah[ks] = *(const short8*)(hsrc + lr * 256 + ((ks * 64 + lk * 16) ^ ((lr & 7) << 4)));

    f32x4 aZ = {0.f, 0.f, 0.f, 0.f}, aR = aZ, aHn = aZ;
#pragma unroll
    for (int ks = 0; ks < 4; ++ks) {
      aZ  = __builtin_amdgcn_mfma_f32_16x16x32_bf16(ah[ks], bwh[0][ks], aZ, 0, 0, 0);
      aR  = __builtin_amdgcn_mfma_f32_16x16x32_bf16(ah[ks], bwh[1][ks], aR, 0, 0, 0);
      aHn = __builtin_amdgcn_mfma_f32_16x16x32_bf16(ah[ks], bwh[2][ks], aHn, 0, 0, 0);
    }
    if (t + 2 < t0 + CH) issue(t + 2 - t0, cur);

    if constexpr (DENSE) {
      if (t > 0) {
        f32x4 aD = {0.f, 0.f, 0.f, 0.f};
#pragma unroll
        for (int ks = 0; ks < 4; ++ks)
          aD = __builtin_amdgcn_mfma_f32_16x16x32_bf16(ah[ks], bwd[ks], aD, 0, 0, 0);
#pragma unroll
        for (int i = 0; i < 4; ++i)
          ob[pp * 2048 + (lk * 4 + i) * 128 + col] = sigm(aD[i] + bdv);
      }
    }

#pragma unroll
    for (int i = 0; i < 4; ++i) {
      const float z = sigm(aZ[i] + bf2f(g0[i]));
      const float r = sigm(aR[i] + bf2f(g1[i]));
      const float n = tanh_fast(bf2f(g2[i]) + r * aHn[i]);
      const float h = z * hreg[i] + (1.f - z) * n;
      hreg[i] = h;
      const int hrow = lk * 4 + i;
      *(short*)(hdst + hrow * 256 + ((col * 2) ^ ((hrow & 7) << 4))) = f2bf(h);
    }

    __builtin_amdgcn_sched_barrier(0);
    asm volatile("s_waitcnt lgkmcnt(0)");
    __builtin_amdgcn_s_barrier();
    __builtin_amdgcn_sched_barrier(0);

    if constexpr (DENSE) {
      if (t > 0) {
        f32x4 v = *(const f32x4*)(ob + pp * 2048 + tid * 4);
        *(f32x4*)(out + ((size_t)(rb * 16 + (tid >> 5)) * Tt + (t - 1)) * Hh + (tid & 31) * 4) = v;
      }
    } else {
      short4v hv = *(const short4v*)(hdst + tid * 8);
      *(short4v*)(hstream + (size_t)((t - t0) * 512 + rb * 16 + (tid >> 5)) * 128 + (tid & 31) * 4) = hv;
    }
  };

  for (int tb = t0; tb < t0 + CH; tb += 2) {
    step(tb, pfA);
    step(tb + 1, pfB);
  }

  {  // save recurrent state for next chunk
    f32x4 sv;
#pragma unroll
    for (int i = 0; i < 4; ++i) sv[i] = hreg[i];
    *(f32x4*)(state + (size_t)(rb * 512 + tid) * 4) = sv;
  }

  if constexpr (DENSE) {
    if (t0 + CH == Tt) {   // emit final row t = Tt-1 from h(Tt-1) in h_buf[0]
      short8 ah[4];
#pragma unroll
      for (int ks = 0; ks < 4; ++ks)
        ah[ks] = *(const short8*)(h_buf + lr * 256 + ((ks * 64 + lk * 16) ^ ((lr & 7) << 4)));
      f32x4 aD = {0.f, 0.f, 0.f, 0.f};
#pragma unroll
      for (int ks = 0; ks < 4; ++ks)
        aD = __builtin_amdgcn_mfma_f32_16x16x32_bf16(ah[ks], bwd[ks], aD, 0, 0, 0);
#pragma unroll
      for (int i = 0; i < 4; ++i)
        out[((size_t)(rb * 16 + lk * 4 + i) * Tt + (Tt - 1)) * Hh + col] = sigm(aD[i] + bdv);
    }
  }
}

struct GArgs { const void* src; char* gx; const char* wxf; const float* bias; int t0; int isx; };
struct SArgs { const char* gx; short* hstream; float* state; const char* whf; int t0; int dense; };

__global__ __launch_bounds__(512, 1) void gemm_multi(GArgs a0, GArgs a1, GArgs a2) {
  __shared__ char at[16384];
  const int g = blockIdx.x >> 9;
  const int wg = blockIdx.x & 511;
  GArgs a = (g == 0) ? a0 : (g == 1 ? a1 : a2);
  if (a.isx) gemm_chunk<2>(a.src, a.t0, a.wxf, a.bias, a.gx, wg, at);
  else       gemm_chunk<4>(a.src, a.t0, a.wxf, a.bias, a.gx, wg, at);
}

__global__ __launch_bounds__(512, 1) void scan_multi(SArgs a0, SArgs a1, SArgs a2,
                                                     const char* __restrict__ wdf,
                                                     const float* __restrict__ bd,
                                                     float* __restrict__ out) {
  __shared__ char hb[8192];
  __shared__ float ob[4096];
  const int g = blockIdx.x >> 5;
  const int rb = blockIdx.x & 31;
  SArgs a = (g == 0) ? a0 : (g == 1 ? a1 : a2);
  if (a.dense) scan_chunk<true >(a.gx, a.whf, a.hstream, a.state, a.t0, wdf, bd, out, rb, hb, ob);
  else         scan_chunk<false>(a.gx, a.whf, a.hstream, a.state, a.t0, wdf, bd, out, rb, hb, ob);
}

}  // namespace

extern "C" void kernel_launch(void* const* d_in, const int* in_sizes, int n_in,
                              void* d_out, int out_size, void* d_ws, size_t ws_size,
                              hipStream_t stream) {
  const float* x   = (const float*)d_in[0];   // [B,T,F]
  const float* Wx0 = (const float*)d_in[1];   // [F,3H]
  const float* Wxr = (const float*)d_in[2];   // [L-1,H,3H]
  const float* Wh  = (const float*)d_in[3];   // [L,H,3H]
  const float* b   = (const float*)d_in[4];   // [L,3H]
  const float* Wd  = (const float*)d_in[5];   // [H,H]
  const float* bd  = (const float*)d_in[6];   // [H]
  float* out = (float*)d_out;

  char* ws = (char*)d_ws;
  char*  WhF   = ws;                               // 294912 B
  char*  WxF   = ws + 294912;                      // 245760 B
  char*  WdF   = ws + 540672;                      // 32768 B
  float* state0 = (float*)(ws + 573440);           // 3 x 262144 B
  float* state1 = state0 + 65536;
  float* state2 = state1 + 65536;
  char*  gx0 = ws + 2097152;                       // 3 x 25165824 B
  char*  gx1 = gx0 + 25165824;
  char*  gx2 = gx1 + 25165824;
  char*  hc  = ws + 2097152 + 3 * 25165824;        // 4 x 8388608 B: [l][parity]

  prep<<<70, 512, 0, stream>>>(Wx0, Wxr, Wh, Wd, WhF, WxF, WdF);

  const size_t WXOFF[3] = {0, 49152, 147456};
  for (int r = 0; r < NCH + 2; ++r) {
    GArgs ga[3]; SArgs sa[3]; int n = 0;
    for (int l = 0; l < 3; ++l) {
      const int k = r - l;
      if (k < 0 || k >= NCH) continue;
      const void* src = (l == 0) ? (const void*)x
                                 : (const void*)(hc + ((size_t)((l - 1) * 2 + (k & 1))) * 8388608);
      char*  gxl = (l == 0) ? gx0 : (l == 1 ? gx1 : gx2);
      float* st  = (l == 0) ? state0 : (l == 1 ? state1 : state2);
      ga[n] = { src, gxl, WxF + WXOFF[l], b + l * Gg, k * CH, l == 0 };
      sa[n] = { gxl, (l < 2) ? (short*)(hc + (size_t)(l * 2 + (k & 1)) * 8388608) : (short*)nullptr,
                st, WhF + (size_t)l * 98304, k * CH, l == 2 };
      ++n;
    }
    for (int i = n; i < 3; ++i) { ga[i] = ga[0]; sa[i] = sa[0]; }
    gemm_multi<<<n * 512, 512, 0, stream>>>(ga[0], ga[1], ga[2]);
    scan_multi<<<n * 32, 512, 0, stream>>>(sa[0], sa[1], sa[2], WdF, bd, out);
  }
}